// Round 10
// baseline (164.582 us; speedup 1.0000x reference)
//
#include <hip/hip_runtime.h>
#include <stdint.h>

// Ragged-batch MHA: N=11136 tokens, 16 segments (contiguous, batch_ids sorted),
// E=256, H=8, hd=32. Pipeline:
//   K1: k_split — vectorized pre-split x->xhi/xlo, qkv_w->whi/wlo, o_w->owb;
//       block 0 also computes the 17 segment offsets (binary search).
//   K2: qkv = x @ qkv_w^T + b, 3-MFMA split path, all-bf16, B tile in LDS,
//       M=192/N=48, A register-prefetched; XCD-affine block swizzle.
//   K3: flash attention, transposed scores, no-max softmax. 128 q-rows/block
//       (2 q-tiles per wave): each staged 64-key K/V chunk serves 2x rows ->
//       barriers, staging, K-LDS reads, loop overhead per row all halve.
//       V LDS rows padded (72 shorts); grid (head, tile) for per-XCD L2 K/V.
//   K4: out = attn @ o_w^T + o_b, owb staged into LDS, A prefetched.

#define N_TOK 11136
#define E 256
#define H 8
#define HD 32

typedef __attribute__((ext_vector_type(8))) __bf16 bf16x8;
typedef __attribute__((ext_vector_type(8))) unsigned short u16x8;
typedef __attribute__((ext_vector_type(4))) float f32x4;

__device__ __forceinline__ unsigned short f2bf(float f) {
  unsigned int u = __float_as_uint(f);
  u = (u + 0x7FFFu + ((u >> 16) & 1u)) >> 16;   // RNE
  return (unsigned short)u;
}
__device__ __forceinline__ float bf2f(unsigned short s) {
  return __uint_as_float(((unsigned int)s) << 16);
}
__device__ __forceinline__ bf16x8 ld8(const unsigned short* p) {
  return *(const bf16x8*)p;
}

// ---------------- K1: vectorized hi/lo split + segment offsets ----------------
__global__ void k_split(const float* __restrict__ x, const float* __restrict__ qw,
                        const float* __restrict__ ow, const int* __restrict__ ids,
                        unsigned short* __restrict__ xhi, unsigned short* __restrict__ xlo,
                        unsigned short* __restrict__ whi, unsigned short* __restrict__ wlo,
                        unsigned short* __restrict__ owb, int* __restrict__ offs) {
  if (blockIdx.x == 0 && threadIdx.x < 17) {
    int b = threadIdx.x, lo = 0, hi = N_TOK;
    while (lo < hi) { int mid = (lo + hi) >> 1; if (ids[mid] < b) lo = mid + 1; else hi = mid; }
    offs[b] = lo;   // lower_bound(b); offs[0]=0, offs[16]=N
  }
  const int NX4 = N_TOK * E / 4;        // 712704
  const int NW4 = 3 * E * E / 4;        // 147456
  const int NO4 = E * E / 4;            // 16384
  int total = NX4 + NW4 + NO4;
  for (int i = blockIdx.x * blockDim.x + threadIdx.x; i < total;
       i += gridDim.x * blockDim.x) {
    if (i < NX4) {
      float4 v = ((const float4*)x)[i];
      ushort4 hv, lv;
      hv.x = f2bf(v.x); lv.x = f2bf(v.x - bf2f(hv.x));
      hv.y = f2bf(v.y); lv.y = f2bf(v.y - bf2f(hv.y));
      hv.z = f2bf(v.z); lv.z = f2bf(v.z - bf2f(hv.z));
      hv.w = f2bf(v.w); lv.w = f2bf(v.w - bf2f(hv.w));
      ((ushort4*)xhi)[i] = hv; ((ushort4*)xlo)[i] = lv;
    } else if (i < NX4 + NW4) {
      int j = i - NX4;
      float4 v = ((const float4*)qw)[j];
      ushort4 hv, lv;
      hv.x = f2bf(v.x); lv.x = f2bf(v.x - bf2f(hv.x));
      hv.y = f2bf(v.y); lv.y = f2bf(v.y - bf2f(hv.y));
      hv.z = f2bf(v.z); lv.z = f2bf(v.z - bf2f(hv.z));
      hv.w = f2bf(v.w); lv.w = f2bf(v.w - bf2f(hv.w));
      ((ushort4*)whi)[j] = hv; ((ushort4*)wlo)[j] = lv;
    } else {
      int j = i - NX4 - NW4;
      float4 v = ((const float4*)ow)[j];
      ushort4 hv;
      hv.x = f2bf(v.x); hv.y = f2bf(v.y); hv.z = f2bf(v.z); hv.w = f2bf(v.w);
      ((ushort4*)owb)[j] = hv;
    }
  }
}

// ---------------- K2: qkv projection ----------------
// Tile M=192 (4 waves x 3 m-tiles of 16), N=48 (3 t-tiles), K=256 (whole).
// Virtual grid 16x64 = 1024 blocks; XCD-affine swizzle: xcd=bid&7 sees all 16
// col-blocks of tiles {xcd, 8+xcd, ..., 56+xcd} -> per-XCD L2 footprint 2.4MB.
#define QK_BSTRIDE 264   // 256 + 8 pad
#define QSCALE (0.17677669529663687f * 1.4426950408889634f)   // 1/sqrt(32)*log2(e)
__global__ __launch_bounds__(256, 3) void k_qkv(
    const unsigned short* __restrict__ xhi, const unsigned short* __restrict__ xlo,
    const unsigned short* __restrict__ whi, const unsigned short* __restrict__ wlo,
    const float* __restrict__ qkv_b,
    unsigned short* __restrict__ Qb, unsigned short* __restrict__ Kb,
    unsigned short* __restrict__ Vt) {
  int bid = blockIdx.x + 16 * blockIdx.y;
  int xcd = bid & 7;
  int j8 = bid >> 3;                      // 0..127
  int colb = j8 & 15;
  int tile = (j8 >> 4) * 8 + xcd;         // 0..63
  if (tile >= 58) return;                 // 58*192 == 11136
  int col0 = colb * 48;
  __shared__ __align__(16) unsigned short Bhi[48 * QK_BSTRIDE];
  __shared__ __align__(16) unsigned short Blo[48 * QK_BSTRIDE];
  int tid = threadIdx.x;
  int w = tid >> 6, lane = tid & 63, m = lane & 15, quad = lane >> 4;
  int rowb = tile * 192 + w * 48;

  // stage pre-split weight tile: 48 rows x 256 cols, 16B copies
  {
    const u16x8* wh8 = (const u16x8*)(whi + (size_t)col0 * E);
    const u16x8* wl8 = (const u16x8*)(wlo + (size_t)col0 * E);
#pragma unroll
    for (int i = 0; i < 6; ++i) {       // 48*32 u16x8 chunks / 256 threads
      int flat = i * 256 + tid;
      int row = flat >> 5, c8 = flat & 31;
      *(u16x8*)(Bhi + row * QK_BSTRIDE + c8 * 8) = wh8[flat];
      *(u16x8*)(Blo + row * QK_BSTRIDE + c8 * 8) = wl8[flat];
    }
  }
  __syncthreads();

  f32x4 acc[3][3] = {};
  bf16x8 ahn[3], aln[3];
#pragma unroll
  for (int mt = 0; mt < 3; ++mt) {      // prefetch kc=0
    const size_t ro = (size_t)(rowb + mt * 16 + m) * E + quad * 8;
    ahn[mt] = ld8(xhi + ro);
    aln[mt] = ld8(xlo + ro);
  }
  for (int kc = 0; kc < 8; ++kc) {
    bf16x8 ah[3], al[3];
#pragma unroll
    for (int mt = 0; mt < 3; ++mt) { ah[mt] = ahn[mt]; al[mt] = aln[mt]; }
    int kon = (kc < 7 ? kc + 1 : kc) * 32 + quad * 8;   // prefetch next kc
#pragma unroll
    for (int mt = 0; mt < 3; ++mt) {
      const size_t ro = (size_t)(rowb + mt * 16 + m) * E + kon;
      ahn[mt] = ld8(xhi + ro);
      aln[mt] = ld8(xlo + ro);
    }
    int ko = kc * 32 + quad * 8;
#pragma unroll
    for (int t = 0; t < 3; ++t) {
      bf16x8 bh = ld8(Bhi + (16 * t + m) * QK_BSTRIDE + ko);
      bf16x8 bl = ld8(Blo + (16 * t + m) * QK_BSTRIDE + ko);
#pragma unroll
      for (int mt = 0; mt < 3; ++mt) {
        acc[mt][t] = __builtin_amdgcn_mfma_f32_16x16x32_bf16(ah[mt], bh, acc[mt][t], 0, 0, 0);
        acc[mt][t] = __builtin_amdgcn_mfma_f32_16x16x32_bf16(ah[mt], bl, acc[mt][t], 0, 0, 0);
        acc[mt][t] = __builtin_amdgcn_mfma_f32_16x16x32_bf16(al[mt], bh, acc[mt][t], 0, 0, 0);
      }
    }
  }
  // epilogue: C layout col=lane&15, row=quad*4+reg. 16-col groups (start mult of 16)
  // never straddle q/k/v 32-boundaries -> wave-uniform routing per t.
#pragma unroll
  for (int t = 0; t < 3; ++t) {
    int j = col0 + 16 * t + m;
    int hd = j / 96;
    int rr = j - hd * 96;
    float bias = qkv_b[j];
#pragma unroll
    for (int mt = 0; mt < 3; ++mt) {
      int tokb = rowb + mt * 16 + quad * 4;
      if (rr < 64) {
        float qsc = (rr < 32) ? QSCALE : 1.0f;   // fold logits scale into Q
        unsigned short* dst = (rr < 32) ? (Qb + (size_t)hd * N_TOK * HD + rr)
                                        : (Kb + (size_t)hd * N_TOK * HD + (rr - 32));
#pragma unroll
        for (int r = 0; r < 4; ++r)
          dst[(size_t)(tokb + r) * HD] = f2bf((acc[mt][t][r] + bias) * qsc);
      } else {
        int d = rr - 64;
        ushort4 pk;
        pk.x = f2bf(acc[mt][t][0] + bias); pk.y = f2bf(acc[mt][t][1] + bias);
        pk.z = f2bf(acc[mt][t][2] + bias); pk.w = f2bf(acc[mt][t][3] + bias);
        *(ushort4*)(Vt + (size_t)(hd * HD + d) * N_TOK + tokb) = pk;
      }
    }
  }
}

// ---------------- K3: flash attention, 128 q-rows/block ----------------
// 4 waves x 2 q-tiles of 16. Each staged 64-key chunk of K/V (shared by the
// whole block, double-buffered) feeds BOTH q-tiles: 4 kf reads -> 8 QK MFMAs,
// 4 vf reads -> 8 PV MFMAs. Per-q-row barrier/staging/loop cost halves vs the
// 64-row version. No-max softmax (|s|<~5 in exp2 domain), raw v_exp_f32.
#define PSTRIDE 72
#define VSTR 72
__global__ __launch_bounds__(256, 4) void k_attn(
    const int* __restrict__ ids, const int* __restrict__ offs,
    const unsigned short* __restrict__ Qb, const unsigned short* __restrict__ Kb,
    const unsigned short* __restrict__ Vt,
    unsigned short* __restrict__ attnb) {
  __shared__ __align__(16) unsigned short Kl[2][64 * 32];   // [buf][key][d]
  __shared__ __align__(16) unsigned short Vl[2][32 * VSTR]; // [buf][d][key+pad]
  __shared__ __align__(16) unsigned short ldsP[8][16 * PSTRIDE];  // [w*2+tile]
  __shared__ int bred[8];
  int tid = threadIdx.x;
  int w = tid >> 6, lane = tid & 63;
  int m = lane & 15, quad = lane >> 4;
  int h = blockIdx.x;                     // x fastest -> XCD affinity by head
  int q0 = blockIdx.y * 128 + w * 16;     // tile0 rows; tile1 = +64
  int tok0 = q0 + m, tok1 = q0 + 64 + m;
  int b0 = ids[tok0], b1 = ids[tok1];
  int st0 = offs[b0], en0 = offs[b0 + 1];
  int st1 = offs[b1], en1 = offs[b1 + 1];
  int kminW = min(st0, st1), kmaxW = max(en0, en1);
  int stM0 = st0, enm0 = en0, stM1 = st1, enm1 = en1;
#pragma unroll
  for (int d = 1; d <= 8; d <<= 1) {      // st/en depend only on m
    kminW = min(kminW, __shfl_xor(kminW, d));
    kmaxW = max(kmaxW, __shfl_xor(kmaxW, d));
    stM0 = max(stM0, __shfl_xor(stM0, d));
    enm0 = min(enm0, __shfl_xor(enm0, d));
    stM1 = max(stM1, __shfl_xor(stM1, d));
    enm1 = min(enm1, __shfl_xor(enm1, d));
  }
  if (lane == 0) { bred[w] = kminW; bred[4 + w] = kmaxW; }
  __syncthreads();
  int kminB = min(min(bred[0], bred[1]), min(bred[2], bred[3]));
  int kmaxB = max(max(bred[4], bred[5]), max(bred[6], bred[7]));
  int k0beg = kminB & ~63;                // N_TOK % 64 == 0: chunk loads in-bounds

  const unsigned short* Kbase = Kb + (size_t)h * N_TOK * HD;
  const unsigned short* Vbase = Vt + (size_t)h * HD * N_TOK;
  bf16x8 qf0 = ld8(Qb + (size_t)(h * N_TOK + tok0) * HD + quad * 8);
  bf16x8 qf1 = ld8(Qb + (size_t)(h * N_TOK + tok1) * HD + quad * 8);
  unsigned short* P0 = ldsP[2 * w];
  unsigned short* P1 = ldsP[2 * w + 1];

  // staging layout: this lane stages 16B of K and 16B of V per chunk
  int krow = w * 16 + (lane >> 2);        // key index within chunk
  int kgof = (lane & 3) * 8;              // d offset
  int vrow = w * 8 + (lane >> 3);         // d row
  int vgof = (lane & 7) * 8;              // key offset within chunk

  // prologue: stage chunk 0 into buf 0
  bf16x8 kg = ld8(Kbase + (size_t)(k0beg + krow) * HD + kgof);
  bf16x8 vg = ld8(Vbase + (size_t)vrow * N_TOK + k0beg + vgof);
  *(bf16x8*)(&Kl[0][krow * 32 + kgof]) = kg;
  *(bf16x8*)(&Vl[0][vrow * VSTR + vgof]) = vg;
  __syncthreads();

  float lsum0 = 0.f, lsum1 = 0.f;
  f32x4 o00 = {}, o01 = {}, o10 = {}, o11 = {};
  int buf = 0;
  for (int k0 = k0beg; k0 < kmaxB; k0 += 64) {
    int k1 = (k0 + 64 < kmaxB) ? (k0 + 64) : k0;  // clamped block-uniform prefetch
    kg = ld8(Kbase + (size_t)(k1 + krow) * HD + kgof);
    vg = ld8(Vbase + (size_t)vrow * N_TOK + k1 + vgof);
    const unsigned short* Kc = &Kl[buf][0];
    const unsigned short* Vc = &Vl[buf][0];
    f32x4 s0[4], s1[4];
#pragma unroll
    for (int i = 0; i < 4; ++i) {
      bf16x8 kf = ld8(Kc + (16 * i + m) * 32 + quad * 8);
      f32x4 z = {};
      s0[i] = __builtin_amdgcn_mfma_f32_16x16x32_bf16(kf, qf0, z, 0, 0, 0);
      s1[i] = __builtin_amdgcn_mfma_f32_16x16x32_bf16(kf, qf1, z, 0, 0, 0);
    }
    int jb = k0 + quad * 4;
    // ---- tile 0 softmax ----
    {
      bool interior = (k0 >= stM0 && k0 + 64 <= enm0);
#pragma unroll
      for (int i = 0; i < 4; ++i) {
        float p[4];
#pragma unroll
        for (int r = 0; r < 4; ++r) {
          float sv = s0[i][r];
          if (!interior) {
            int j = jb + 16 * i + r;
            sv = (j >= st0 && j < en0) ? sv : -3e38f;   // v_exp(-3e38) == 0
          }
          float e;
          asm("v_exp_f32 %0, %1" : "=v"(e) : "v"(sv));
          p[r] = e;
        }
        lsum0 += (p[0] + p[1]) + (p[2] + p[3]);
        unsigned int c0 = __float_as_uint(p[0]) + 0x8000u;
        unsigned int c1 = __float_as_uint(p[1]) + 0x8000u;
        unsigned int c2 = __float_as_uint(p[2]) + 0x8000u;
        unsigned int c3 = __float_as_uint(p[3]) + 0x8000u;
        uint2 pk;
        pk.x = (c1 & 0xFFFF0000u) | (c0 >> 16);
        pk.y = (c3 & 0xFFFF0000u) | (c2 >> 16);
        *(uint2*)(P0 + m * PSTRIDE + 16 * i + quad * 4) = pk;
      }
    }
    // ---- tile 1 softmax ----
    {
      bool interior = (k0 >= stM1 && k0 + 64 <= enm1);
#pragma unroll
      for (int i = 0; i < 4; ++i) {
        float p[4];
#pragma unroll
        for (int r = 0; r < 4; ++r) {
          float sv = s1[i][r];
          if (!interior) {
            int j = jb + 16 * i + r;
            sv = (j >= st1 && j < en1) ? sv : -3e38f;
          }
          float e;
          asm("v_exp_f32 %0, %1" : "=v"(e) : "v"(sv));
          p[r] = e;
        }
        lsum1 += (p[0] + p[1]) + (p[2] + p[3]);
        unsigned int c0 = __float_as_uint(p[0]) + 0x8000u;
        unsigned int c1 = __float_as_uint(p[1]) + 0x8000u;
        unsigned int c2 = __float_as_uint(p[2]) + 0x8000u;
        unsigned int c3 = __float_as_uint(p[3]) + 0x8000u;
        uint2 pk;
        pk.x = (c1 & 0xFFFF0000u) | (c0 >> 16);
        pk.y = (c3 & 0xFFFF0000u) | (c2 >> 16);
        *(uint2*)(P1 + m * PSTRIDE + 16 * i + quad * 4) = pk;
      }
    }
    // ---- PV: shared V reads feed both tiles ----
#pragma unroll
    for (int c = 0; c < 2; ++c) {         // two 32-key sub-chunks
      bf16x8 vf0 = ld8(Vc + m * VSTR + 32 * c + quad * 8);          // A: V[d][k]
      bf16x8 vf1 = ld8(Vc + (16 + m) * VSTR + 32 * c + quad * 8);
      bf16x8 pf0 = ld8(P0 + m * PSTRIDE + 32 * c + quad * 8);       // B: P^T[q][k]
      bf16x8 pf1 = ld8(P1 + m * PSTRIDE + 32 * c + quad * 8);
      o00 = __builtin_amdgcn_mfma_f32_16x16x32_bf16(vf0, pf0, o00, 0, 0, 0);
      o01 = __builtin_amdgcn_mfma_f32_16x16x32_bf16(vf1, pf0, o01, 0, 0, 0);
      o10 = __builtin_amdgcn_mfma_f32_16x16x32_bf16(vf0, pf1, o10, 0, 0, 0);
      o11 = __builtin_amdgcn_mfma_f32_16x16x32_bf16(vf1, pf1, o11, 0, 0, 0);
    }
    // stage next chunk into the other buffer (written this iter, read next)
    *(bf16x8*)(&Kl[buf ^ 1][krow * 32 + kgof]) = kg;
    *(bf16x8*)(&Vl[buf ^ 1][vrow * VSTR + vgof]) = vg;
    __syncthreads();
    buf ^= 1;
  }
  lsum0 += __shfl_xor(lsum0, 16); lsum0 += __shfl_xor(lsum0, 32);
  lsum1 += __shfl_xor(lsum1, 16); lsum1 += __shfl_xor(lsum1, 32);
  float inv0 = 1.0f / lsum0, inv1 = 1.0f / lsum1;
  ushort4 pk0, pk1;
  pk0.x = f2bf(o00[0] * inv0); pk0.y = f2bf(o00[1] * inv0);
  pk0.z = f2bf(o00[2] * inv0); pk0.w = f2bf(o00[3] * inv0);
  pk1.x = f2bf(o01[0] * inv0); pk1.y = f2bf(o01[1] * inv0);
  pk1.z = f2bf(o01[2] * inv0); pk1.w = f2bf(o01[3] * inv0);
  *(ushort4*)(attnb + (size_t)tok0 * E + h * HD + quad * 4) = pk0;
  *(ushort4*)(attnb + (size_t)tok0 * E + h * HD + 16 + quad * 4) = pk1;
  pk0.x = f2bf(o10[0] * inv1); pk0.y = f2bf(o10[1] * inv1);
  pk0.z = f2bf(o10[2] * inv1); pk0.w = f2bf(o10[3] * inv1);
  pk1.x = f2bf(o11[0] * inv1); pk1.y = f2bf(o11[1] * inv1);
  pk1.z = f2bf(o11[2] * inv1); pk1.w = f2bf(o11[3] * inv1);
  *(ushort4*)(attnb + (size_t)tok1 * E + h * HD + quad * 4) = pk0;
  *(ushort4*)(attnb + (size_t)tok1 * E + h * HD + 16 + quad * 4) = pk1;
}

// ---------------- K4: output projection ----------------
// Tile M=64 (4 waves x 1 m-tile), N=64 (4 t-tiles), K=256 whole.
// Pre-converted owb copied into LDS; A-loads register-prefetched one kc ahead.
__global__ __launch_bounds__(256, 4) void k_oproj(
    const unsigned short* __restrict__ attnb, const unsigned short* __restrict__ owb,
    const float* __restrict__ ob, float* __restrict__ out) {
  __shared__ __align__(16) unsigned short Bo[64 * QK_BSTRIDE];
  int tid = threadIdx.x;
  int w = tid >> 6, lane = tid & 63, m = lane & 15, quad = lane >> 4;
  int tok0 = blockIdx.x * 64, col0 = blockIdx.y * 64;
  {
    const u16x8* o8 = (const u16x8*)(owb + (size_t)col0 * E);
#pragma unroll
    for (int i = 0; i < 8; ++i) {         // 64*32 u16x8 chunks / 256 threads
      int flat = i * 256 + tid;
      int row = flat >> 5, c8 = flat & 31;
      *(u16x8*)(Bo + row * QK_BSTRIDE + c8 * 8) = o8[flat];
    }
  }
  __syncthreads();
  f32x4 acc[4] = {};
  int arow = tok0 + 16 * w + m;
  const unsigned short* abase = attnb + (size_t)arow * E + quad * 8;
  bf16x8 an = ld8(abase);                 // prefetch kc=0
  for (int kc = 0; kc < 8; ++kc) {
    bf16x8 a = an;
    an = ld8(abase + (kc < 7 ? kc + 1 : kc) * 32);
    int ko = kc * 32 + quad * 8;
#pragma unroll
    for (int t = 0; t < 4; ++t) {
      bf16x8 b = ld8(Bo + (16 * t + m) * QK_BSTRIDE + ko);
      acc[t] = __builtin_amdgcn_mfma_f32_16x16x32_bf16(a, b, acc[t], 0, 0, 0);
    }
  }
#pragma unroll
  for (int t = 0; t < 4; ++t) {
    int j = col0 + 16 * t + m;
    float bias = ob[j];
#pragma unroll
    for (int r = 0; r < 4; ++r) {
      int tok = tok0 + 16 * w + quad * 4 + r;
      out[(size_t)tok * E + j] = acc[t][r] + bias;
    }
  }
}

extern "C" void kernel_launch(void* const* d_in, const int* in_sizes, int n_in,
                              void* d_out, int out_size, void* d_ws, size_t ws_size,
                              hipStream_t stream) {
  const float* x   = (const float*)d_in[0];
  const int*   ids = (const int*)d_in[1];
  const float* qw  = (const float*)d_in[2];
  const float* qb  = (const float*)d_in[3];
  const float* ow  = (const float*)d_in[4];
  const float* ob  = (const float*)d_in[5];
  float* out = (float*)d_out;

  char* p = (char*)d_ws;
  auto alloc = [&](size_t bytes) {
    char* r = p;
    p += (bytes + 255) & ~(size_t)255;
    return r;
  };
  int* offs = (int*)alloc(32 * sizeof(int));
  unsigned short* xhi = (unsigned short*)alloc((size_t)N_TOK * E * 2);
  unsigned short* xlo = (unsigned short*)alloc((size_t)N_TOK * E * 2);
  unsigned short* whi = (unsigned short*)alloc((size_t)3 * E * E * 2);
  unsigned short* wlo = (unsigned short*)alloc((size_t)3 * E * E * 2);
  unsigned short* owb = (unsigned short*)alloc((size_t)E * E * 2);
  unsigned short* Qb  = (unsigned short*)alloc((size_t)N_TOK * E * 2);
  unsigned short* Kb  = (unsigned short*)alloc((size_t)N_TOK * E * 2);
  unsigned short* Vt  = (unsigned short*)alloc((size_t)N_TOK * E * 2);
  unsigned short* att = (unsigned short*)alloc((size_t)N_TOK * E * 2);

  k_split<<<dim3(1712), dim3(256), 0, stream>>>(x, qw, ow, ids, xhi, xlo, whi, wlo, owb, offs);
  k_qkv<<<dim3(16, 64), dim3(256), 0, stream>>>(xhi, xlo, whi, wlo, qb, Qb, Kb, Vt);
  k_attn<<<dim3(H, N_TOK / 128), dim3(256), 0, stream>>>(ids, offs, Qb, Kb, Vt, att);
  k_oproj<<<dim3(N_TOK / 64, E / 64), dim3(256), 0, stream>>>(att, owb, ob, out);
}

// Round 12
// 163.866 us; speedup vs baseline: 1.0044x; 1.0044x over previous
//
#include <hip/hip_runtime.h>
#include <stdint.h>

// Ragged-batch MHA: N=11136 tokens, 16 segments (contiguous, batch_ids sorted),
// E=256, H=8, hd=32. Pipeline:
//   K1: k_split — vectorized pre-split x->xhi/xlo, qkv_w->whi/wlo, o_w->owb;
//       block 0 also computes the 17 segment offsets (binary search).
//   K2: qkv = x @ qkv_w^T + b, 3-MFMA split path, all-bf16, B tile in LDS,
//       M=192/N=48, A register-prefetched; XCD-affine block swizzle.
//   K3: flash attention, transposed scores, no-max softmax, 64 q-rows/block,
//       KEY-SPLIT KS=2 (softmax w/o max is additive): each split writes
//       unnormalized fp32 partial O + partial lsum. Doubles block count
//       (2784, 10.9/CU) -> halves serial chain, smooths segment-length tail.
//   K4: out = ((O0+O1)*inv(l0+l1)) @ o_w^T + o_b — combine folded into A-staging.

#define N_TOK 11136
#define E 256
#define H 8
#define HD 32

typedef __attribute__((ext_vector_type(8))) __bf16 bf16x8;
typedef __attribute__((ext_vector_type(8))) unsigned short u16x8;
typedef __attribute__((ext_vector_type(4))) float f32x4;

__device__ __forceinline__ unsigned short f2bf(float f) {
  unsigned int u = __float_as_uint(f);
  u = (u + 0x7FFFu + ((u >> 16) & 1u)) >> 16;   // RNE
  return (unsigned short)u;
}
__device__ __forceinline__ float bf2f(unsigned short s) {
  return __uint_as_float(((unsigned int)s) << 16);
}
__device__ __forceinline__ bf16x8 ld8(const unsigned short* p) {
  return *(const bf16x8*)p;
}

// ---------------- K1: vectorized hi/lo split + segment offsets ----------------
__global__ void k_split(const float* __restrict__ x, const float* __restrict__ qw,
                        const float* __restrict__ ow, const int* __restrict__ ids,
                        unsigned short* __restrict__ xhi, unsigned short* __restrict__ xlo,
                        unsigned short* __restrict__ whi, unsigned short* __restrict__ wlo,
                        unsigned short* __restrict__ owb, int* __restrict__ offs) {
  if (blockIdx.x == 0 && threadIdx.x < 17) {
    int b = threadIdx.x, lo = 0, hi = N_TOK;
    while (lo < hi) { int mid = (lo + hi) >> 1; if (ids[mid] < b) lo = mid + 1; else hi = mid; }
    offs[b] = lo;   // lower_bound(b); offs[0]=0, offs[16]=N
  }
  const int NX4 = N_TOK * E / 4;        // 712704
  const int NW4 = 3 * E * E / 4;        // 147456
  const int NO4 = E * E / 4;            // 16384
  int total = NX4 + NW4 + NO4;
  for (int i = blockIdx.x * blockDim.x + threadIdx.x; i < total;
       i += gridDim.x * blockDim.x) {
    if (i < NX4) {
      float4 v = ((const float4*)x)[i];
      ushort4 hv, lv;
      hv.x = f2bf(v.x); lv.x = f2bf(v.x - bf2f(hv.x));
      hv.y = f2bf(v.y); lv.y = f2bf(v.y - bf2f(hv.y));
      hv.z = f2bf(v.z); lv.z = f2bf(v.z - bf2f(hv.z));
      hv.w = f2bf(v.w); lv.w = f2bf(v.w - bf2f(hv.w));
      ((ushort4*)xhi)[i] = hv; ((ushort4*)xlo)[i] = lv;
    } else if (i < NX4 + NW4) {
      int j = i - NX4;
      float4 v = ((const float4*)qw)[j];
      ushort4 hv, lv;
      hv.x = f2bf(v.x); lv.x = f2bf(v.x - bf2f(hv.x));
      hv.y = f2bf(v.y); lv.y = f2bf(v.y - bf2f(hv.y));
      hv.z = f2bf(v.z); lv.z = f2bf(v.z - bf2f(hv.z));
      hv.w = f2bf(v.w); lv.w = f2bf(v.w - bf2f(hv.w));
      ((ushort4*)whi)[j] = hv; ((ushort4*)wlo)[j] = lv;
    } else {
      int j = i - NX4 - NW4;
      float4 v = ((const float4*)ow)[j];
      ushort4 hv;
      hv.x = f2bf(v.x); hv.y = f2bf(v.y); hv.z = f2bf(v.z); hv.w = f2bf(v.w);
      ((ushort4*)owb)[j] = hv;
    }
  }
}

// ---------------- K2: qkv projection ----------------
// Tile M=192 (4 waves x 3 m-tiles of 16), N=48 (3 t-tiles), K=256 (whole).
// Virtual grid 16x64 = 1024 blocks; XCD-affine swizzle: xcd=bid&7 sees all 16
// col-blocks of tiles {xcd, 8+xcd, ..., 56+xcd} -> per-XCD L2 footprint 2.4MB.
#define QK_BSTRIDE 264   // 256 + 8 pad
#define QSCALE (0.17677669529663687f * 1.4426950408889634f)   // 1/sqrt(32)*log2(e)
__global__ __launch_bounds__(256, 3) void k_qkv(
    const unsigned short* __restrict__ xhi, const unsigned short* __restrict__ xlo,
    const unsigned short* __restrict__ whi, const unsigned short* __restrict__ wlo,
    const float* __restrict__ qkv_b,
    unsigned short* __restrict__ Qb, unsigned short* __restrict__ Kb,
    unsigned short* __restrict__ Vt) {
  int bid = blockIdx.x + 16 * blockIdx.y;
  int xcd = bid & 7;
  int j8 = bid >> 3;                      // 0..127
  int colb = j8 & 15;
  int tile = (j8 >> 4) * 8 + xcd;         // 0..63
  if (tile >= 58) return;                 // 58*192 == 11136
  int col0 = colb * 48;
  __shared__ __align__(16) unsigned short Bhi[48 * QK_BSTRIDE];
  __shared__ __align__(16) unsigned short Blo[48 * QK_BSTRIDE];
  int tid = threadIdx.x;
  int w = tid >> 6, lane = tid & 63, m = lane & 15, quad = lane >> 4;
  int rowb = tile * 192 + w * 48;

  // stage pre-split weight tile: 48 rows x 256 cols, 16B copies
  {
    const u16x8* wh8 = (const u16x8*)(whi + (size_t)col0 * E);
    const u16x8* wl8 = (const u16x8*)(wlo + (size_t)col0 * E);
#pragma unroll
    for (int i = 0; i < 6; ++i) {       // 48*32 u16x8 chunks / 256 threads
      int flat = i * 256 + tid;
      int row = flat >> 5, c8 = flat & 31;
      *(u16x8*)(Bhi + row * QK_BSTRIDE + c8 * 8) = wh8[flat];
      *(u16x8*)(Blo + row * QK_BSTRIDE + c8 * 8) = wl8[flat];
    }
  }
  __syncthreads();

  f32x4 acc[3][3] = {};
  bf16x8 ahn[3], aln[3];
#pragma unroll
  for (int mt = 0; mt < 3; ++mt) {      // prefetch kc=0
    const size_t ro = (size_t)(rowb + mt * 16 + m) * E + quad * 8;
    ahn[mt] = ld8(xhi + ro);
    aln[mt] = ld8(xlo + ro);
  }
  for (int kc = 0; kc < 8; ++kc) {
    bf16x8 ah[3], al[3];
#pragma unroll
    for (int mt = 0; mt < 3; ++mt) { ah[mt] = ahn[mt]; al[mt] = aln[mt]; }
    int kon = (kc < 7 ? kc + 1 : kc) * 32 + quad * 8;   // prefetch next kc
#pragma unroll
    for (int mt = 0; mt < 3; ++mt) {
      const size_t ro = (size_t)(rowb + mt * 16 + m) * E + kon;
      ahn[mt] = ld8(xhi + ro);
      aln[mt] = ld8(xlo + ro);
    }
    int ko = kc * 32 + quad * 8;
#pragma unroll
    for (int t = 0; t < 3; ++t) {
      bf16x8 bh = ld8(Bhi + (16 * t + m) * QK_BSTRIDE + ko);
      bf16x8 bl = ld8(Blo + (16 * t + m) * QK_BSTRIDE + ko);
#pragma unroll
      for (int mt = 0; mt < 3; ++mt) {
        acc[mt][t] = __builtin_amdgcn_mfma_f32_16x16x32_bf16(ah[mt], bh, acc[mt][t], 0, 0, 0);
        acc[mt][t] = __builtin_amdgcn_mfma_f32_16x16x32_bf16(ah[mt], bl, acc[mt][t], 0, 0, 0);
        acc[mt][t] = __builtin_amdgcn_mfma_f32_16x16x32_bf16(al[mt], bh, acc[mt][t], 0, 0, 0);
      }
    }
  }
  // epilogue: C layout col=lane&15, row=quad*4+reg. 16-col groups (start mult of 16)
  // never straddle q/k/v 32-boundaries -> wave-uniform routing per t.
#pragma unroll
  for (int t = 0; t < 3; ++t) {
    int j = col0 + 16 * t + m;
    int hd = j / 96;
    int rr = j - hd * 96;
    float bias = qkv_b[j];
#pragma unroll
    for (int mt = 0; mt < 3; ++mt) {
      int tokb = rowb + mt * 16 + quad * 4;
      if (rr < 64) {
        float qsc = (rr < 32) ? QSCALE : 1.0f;   // fold logits scale into Q
        unsigned short* dst = (rr < 32) ? (Qb + (size_t)hd * N_TOK * HD + rr)
                                        : (Kb + (size_t)hd * N_TOK * HD + (rr - 32));
#pragma unroll
        for (int r = 0; r < 4; ++r)
          dst[(size_t)(tokb + r) * HD] = f2bf((acc[mt][t][r] + bias) * qsc);
      } else {
        int d = rr - 64;
        ushort4 pk;
        pk.x = f2bf(acc[mt][t][0] + bias); pk.y = f2bf(acc[mt][t][1] + bias);
        pk.z = f2bf(acc[mt][t][2] + bias); pk.w = f2bf(acc[mt][t][3] + bias);
        *(ushort4*)(Vt + (size_t)(hd * HD + d) * N_TOK + tokb) = pk;
      }
    }
  }
}

// ---------------- K3: flash attention, key-split partials ----------------
// 64 q-rows/block (round-9 shape), grid (head, tile, ks=2). Split ks processes
// half the 64-key chunks; no-max softmax is additive, so each split emits
// unnormalized fp32 O^T partial + lsum partial. Block-shared double-buffered
// K/V LDS staging; V rows padded (VSTR) for conflict-free PV reads.
#define PSTRIDE 72
#define VSTR 72
__global__ __launch_bounds__(256, 4) void k_attn(
    const int* __restrict__ ids, const int* __restrict__ offs,
    const unsigned short* __restrict__ Qb, const unsigned short* __restrict__ Kb,
    const unsigned short* __restrict__ Vt,
    float* __restrict__ Opart, float* __restrict__ Ls) {
  __shared__ __align__(16) unsigned short Kl[2][64 * 32];   // [buf][key][d]
  __shared__ __align__(16) unsigned short Vl[2][32 * VSTR]; // [buf][d][key+pad]
  __shared__ __align__(16) unsigned short ldsP[4][16 * PSTRIDE];
  __shared__ int bred[8];
  int tid = threadIdx.x;
  int w = tid >> 6, lane = tid & 63;
  int m = lane & 15, quad = lane >> 4;
  int h = blockIdx.x;                     // x fastest -> XCD affinity by head
  int ks = blockIdx.z;
  int q0 = blockIdx.y * 64 + w * 16;
  unsigned short* P = ldsP[w];
  int tok = q0 + m;                       // this lane's q-row
  int b = ids[tok];
  int st = offs[b], en = offs[b + 1];
  int kmin = st, kmax = en, stM = st, enm = en;
#pragma unroll
  for (int d = 1; d <= 8; d <<= 1) {      // st/en depend only on m
    kmin = min(kmin, __shfl_xor(kmin, d));
    kmax = max(kmax, __shfl_xor(kmax, d));
    stM  = max(stM,  __shfl_xor(stM,  d));
    enm  = min(enm,  __shfl_xor(enm,  d));
  }
  if (lane == 0) { bred[w] = kmin; bred[4 + w] = kmax; }
  __syncthreads();
  int kminB = min(min(bred[0], bred[1]), min(bred[2], bred[3]));
  int kmaxB = max(max(bred[4], bred[5]), max(bred[6], bred[7]));
  int k0beg = kminB & ~63;
  int nch = (kmaxB - k0beg + 63) >> 6;    // >= 1
  int half = (nch + 1) >> 1;
  int cs = ks ? half : 0;
  int ce = ks ? nch : half;               // ks=1 may be empty (nch==1)

  const unsigned short* Kbase = Kb + (size_t)h * N_TOK * HD;
  const unsigned short* Vbase = Vt + (size_t)h * HD * N_TOK;
  bf16x8 qf = ld8(Qb + (size_t)(h * N_TOK + tok) * HD + quad * 8);

  // staging layout: this lane stages 16B of K and 16B of V per chunk
  int krow = w * 16 + (lane >> 2);        // key index within chunk
  int kgof = (lane & 3) * 8;              // d offset
  int vrow = w * 8 + (lane >> 3);         // d row
  int vgof = (lane & 7) * 8;              // key offset within chunk

  // prologue: stage first chunk of this split (clamped in-bounds)
  int kpro = k0beg + min(cs, nch - 1) * 64;
  bf16x8 kg = ld8(Kbase + (size_t)(kpro + krow) * HD + kgof);
  bf16x8 vg = ld8(Vbase + (size_t)vrow * N_TOK + kpro + vgof);
  *(bf16x8*)(&Kl[0][krow * 32 + kgof]) = kg;
  *(bf16x8*)(&Vl[0][vrow * VSTR + vgof]) = vg;
  __syncthreads();

  float lsum = 0.f;
  f32x4 o0 = {}, o1 = {};
  int buf = 0;
  for (int ci = cs; ci < ce; ++ci) {
    int k0 = k0beg + ci * 64;
    int k1 = (ci + 1 < ce) ? (k0 + 64) : k0;      // clamped block-uniform prefetch
    kg = ld8(Kbase + (size_t)(k1 + krow) * HD + kgof);
    vg = ld8(Vbase + (size_t)vrow * N_TOK + k1 + vgof);
    const unsigned short* Kc = &Kl[buf][0];
    const unsigned short* Vc = &Vl[buf][0];
    f32x4 s[4];
#pragma unroll
    for (int i = 0; i < 4; ++i) {
      bf16x8 kf = ld8(Kc + (16 * i + m) * 32 + quad * 8);
      f32x4 z = {};
      s[i] = __builtin_amdgcn_mfma_f32_16x16x32_bf16(kf, qf, z, 0, 0, 0);
    }
    bool interior = (k0 >= stM && k0 + 64 <= enm);
    int jb = k0 + quad * 4;
#pragma unroll
    for (int i = 0; i < 4; ++i) {
      float p[4];
#pragma unroll
      for (int r = 0; r < 4; ++r) {
        float sv = s[i][r];
        if (!interior) {
          int j = jb + 16 * i + r;
          sv = (j >= st && j < en) ? sv : -3e38f;   // v_exp(-3e38) == 0
        }
        float e;
        asm("v_exp_f32 %0, %1" : "=v"(e) : "v"(sv));
        p[r] = e;
      }
      lsum += (p[0] + p[1]) + (p[2] + p[3]);
      unsigned int b0 = __float_as_uint(p[0]) + 0x8000u;
      unsigned int b1 = __float_as_uint(p[1]) + 0x8000u;
      unsigned int b2 = __float_as_uint(p[2]) + 0x8000u;
      unsigned int b3 = __float_as_uint(p[3]) + 0x8000u;
      uint2 pk;
      pk.x = (b1 & 0xFFFF0000u) | (b0 >> 16);
      pk.y = (b3 & 0xFFFF0000u) | (b2 >> 16);
      *(uint2*)(P + m * PSTRIDE + 16 * i + quad * 4) = pk;   // P^T[q=m][key]
    }
#pragma unroll
    for (int c = 0; c < 2; ++c) {         // two 32-key sub-chunks
      bf16x8 pf  = ld8(P + m * PSTRIDE + 32 * c + quad * 8);        // B: P^T[q][k]
      bf16x8 vf0 = ld8(Vc + m * VSTR + 32 * c + quad * 8);          // A: V[d][k]
      bf16x8 vf1 = ld8(Vc + (16 + m) * VSTR + 32 * c + quad * 8);
      o0 = __builtin_amdgcn_mfma_f32_16x16x32_bf16(vf0, pf, o0, 0, 0, 0);  // d 0..15
      o1 = __builtin_amdgcn_mfma_f32_16x16x32_bf16(vf1, pf, o1, 0, 0, 0);  // d 16..31
    }
    *(bf16x8*)(&Kl[buf ^ 1][krow * 32 + kgof]) = kg;
    *(bf16x8*)(&Vl[buf ^ 1][vrow * VSTR + vgof]) = vg;
    __syncthreads();
    buf ^= 1;
  }
  lsum += __shfl_xor(lsum, 16);
  lsum += __shfl_xor(lsum, 32);           // quads hold disjoint key partial sums
  // unnormalized fp32 partials: O^T col=q(m)=tok, row=d=quad*4+r (+16 for o1)
  float* Op = Opart + (size_t)ks * N_TOK * E;
  *(f32x4*)(Op + (size_t)tok * E + h * HD + quad * 4) = o0;
  *(f32x4*)(Op + (size_t)tok * E + h * HD + 16 + quad * 4) = o1;
  if (quad == 0) Ls[(size_t)(ks * H + h) * N_TOK + tok] = lsum;
}

// ---------------- K4: output projection + split combine ----------------
// A[tok][kc*32+..] = (O0+O1) * inv(l0+l1), computed in-register during staging
// (kc == head index since HD=32). B = owb tile in LDS. M=64, N=64, K=256.
__global__ __launch_bounds__(256, 4) void k_oproj(
    const float* __restrict__ Opart, const float* __restrict__ Ls,
    const unsigned short* __restrict__ owb,
    const float* __restrict__ ob, float* __restrict__ out) {
  __shared__ __align__(16) unsigned short Bo[64 * QK_BSTRIDE];
  int tid = threadIdx.x;
  int w = tid >> 6, lane = tid & 63, m = lane & 15, quad = lane >> 4;
  int tok0 = blockIdx.x * 64, col0 = blockIdx.y * 64;
  {
    const u16x8* o8 = (const u16x8*)(owb + (size_t)col0 * E);
#pragma unroll
    for (int i = 0; i < 8; ++i) {         // 64*32 u16x8 chunks / 256 threads
      int flat = i * 256 + tid;
      int row = flat >> 5, c8 = flat & 31;
      *(u16x8*)(Bo + row * QK_BSTRIDE + c8 * 8) = o8[flat];
    }
  }
  __syncthreads();
  int arow = tok0 + 16 * w + m;
  // per-head inverse combined lsum
  float invl[8];
#pragma unroll
  for (int hh = 0; hh < 8; ++hh) {
    float l0 = Ls[(size_t)hh * N_TOK + arow];
    float l1 = Ls[(size_t)(8 + hh) * N_TOK + arow];
    invl[hh] = 1.0f / (l0 + l1);
  }
  const float* a0 = Opart + (size_t)arow * E + quad * 8;
  const float* a1 = Opart + (size_t)N_TOK * E + (size_t)arow * E + quad * 8;
  f32x4 acc[4] = {};
  float4 nu0 = *(const float4*)(a0), nu1 = *(const float4*)(a0 + 4);
  float4 nv0 = *(const float4*)(a1), nv1 = *(const float4*)(a1 + 4);
  for (int kc = 0; kc < 8; ++kc) {
    float4 u0 = nu0, u1 = nu1, v0 = nv0, v1 = nv1;
    int kn = (kc < 7 ? kc + 1 : kc) * 32;
    nu0 = *(const float4*)(a0 + kn); nu1 = *(const float4*)(a0 + kn + 4);
    nv0 = *(const float4*)(a1 + kn); nv1 = *(const float4*)(a1 + kn + 4);
    float iv = invl[kc];
    u16x8 ar;
    ar[0] = f2bf((u0.x + v0.x) * iv); ar[1] = f2bf((u0.y + v0.y) * iv);
    ar[2] = f2bf((u0.z + v0.z) * iv); ar[3] = f2bf((u0.w + v0.w) * iv);
    ar[4] = f2bf((u1.x + v1.x) * iv); ar[5] = f2bf((u1.y + v1.y) * iv);
    ar[6] = f2bf((u1.z + v1.z) * iv); ar[7] = f2bf((u1.w + v1.w) * iv);
    bf16x8 a = __builtin_bit_cast(bf16x8, ar);
    int ko = kc * 32 + quad * 8;
#pragma unroll
    for (int t = 0; t < 4; ++t) {
      bf16x8 bfr = ld8(Bo + (16 * t + m) * QK_BSTRIDE + ko);
      acc[t] = __builtin_amdgcn_mfma_f32_16x16x32_bf16(a, bfr, acc[t], 0, 0, 0);
    }
  }
#pragma unroll
  for (int t = 0; t < 4; ++t) {
    int j = col0 + 16 * t + m;
    float bias = ob[j];
#pragma unroll
    for (int r = 0; r < 4; ++r) {
      int tok = tok0 + 16 * w + quad * 4 + r;
      out[(size_t)tok * E + j] = acc[t][r] + bias;
    }
  }
}

extern "C" void kernel_launch(void* const* d_in, const int* in_sizes, int n_in,
                              void* d_out, int out_size, void* d_ws, size_t ws_size,
                              hipStream_t stream) {
  const float* x   = (const float*)d_in[0];
  const int*   ids = (const int*)d_in[1];
  const float* qw  = (const float*)d_in[2];
  const float* qb  = (const float*)d_in[3];
  const float* ow  = (const float*)d_in[4];
  const float* ob  = (const float*)d_in[5];
  float* out = (float*)d_out;

  char* p = (char*)d_ws;
  auto alloc = [&](size_t bytes) {
    char* r = p;
    p += (bytes + 255) & ~(size_t)255;
    return r;
  };
  int* offs = (int*)alloc(32 * sizeof(int));
  unsigned short* xhi = (unsigned short*)alloc((size_t)N_TOK * E * 2);
  unsigned short* xlo = (unsigned short*)alloc((size_t)N_TOK * E * 2);
  unsigned short* whi = (unsigned short*)alloc((size_t)3 * E * E * 2);
  unsigned short* wlo = (unsigned short*)alloc((size_t)3 * E * E * 2);
  unsigned short* owb = (unsigned short*)alloc((size_t)E * E * 2);
  unsigned short* Qb  = (unsigned short*)alloc((size_t)N_TOK * E * 2);
  unsigned short* Kb  = (unsigned short*)alloc((size_t)N_TOK * E * 2);
  unsigned short* Vt  = (unsigned short*)alloc((size_t)N_TOK * E * 2);
  float* Opart = (float*)alloc((size_t)2 * N_TOK * E * 4);
  float* Ls    = (float*)alloc((size_t)2 * H * N_TOK * 4);

  k_split<<<dim3(1712), dim3(256), 0, stream>>>(x, qw, ow, ids, xhi, xlo, whi, wlo, owb, offs);
  k_qkv<<<dim3(16, 64), dim3(256), 0, stream>>>(xhi, xlo, whi, wlo, qb, Qb, Kb, Vt);
  k_attn<<<dim3(H, N_TOK / 64, 2), dim3(256), 0, stream>>>(ids, offs, Qb, Kb, Vt, Opart, Ls);
  k_oproj<<<dim3(N_TOK / 64, E / 64), dim3(256), 0, stream>>>(Opart, Ls, owb, ob, out);
}

// Round 13
// 159.523 us; speedup vs baseline: 1.0317x; 1.0272x over previous
//
#include <hip/hip_runtime.h>
#include <stdint.h>

// Ragged-batch MHA: N=11136 tokens, 16 segments (contiguous, batch_ids sorted),
// E=256, H=8, hd=32. Pipeline:
//   K1: k_split — vectorized pre-split x->xhi/xlo, qkv_w->whi/wlo, o_w->owb;
//       block 0 also computes the 17 segment offsets (binary search).
//   K2: qkv = x @ qkv_w^T + b, 3-MFMA split path, all-bf16, B tile in LDS,
//       M=192/N=32 (LDS 33.8KB -> 4 blocks/CU), A register-prefetched;
//       XCD-affine block swizzle (per-XCD footprint 2.4MB -> L2-resident).
//   K3: flash attention, transposed scores, no-max softmax, 64 q-rows/block
//       (round-9 optimum), block-shared double-buffered K/V LDS staging,
//       V rows padded (VSTR=72), grid (head, tile) for per-XCD L2 K/V.
//   K4: out = attn @ o_w^T + o_b, owb staged into LDS, A prefetched.

#define N_TOK 11136
#define E 256
#define H 8
#define HD 32

typedef __attribute__((ext_vector_type(8))) __bf16 bf16x8;
typedef __attribute__((ext_vector_type(8))) unsigned short u16x8;
typedef __attribute__((ext_vector_type(4))) float f32x4;

__device__ __forceinline__ unsigned short f2bf(float f) {
  unsigned int u = __float_as_uint(f);
  u = (u + 0x7FFFu + ((u >> 16) & 1u)) >> 16;   // RNE
  return (unsigned short)u;
}
__device__ __forceinline__ float bf2f(unsigned short s) {
  return __uint_as_float(((unsigned int)s) << 16);
}
__device__ __forceinline__ bf16x8 ld8(const unsigned short* p) {
  return *(const bf16x8*)p;
}

// ---------------- K1: vectorized hi/lo split + segment offsets ----------------
__global__ void k_split(const float* __restrict__ x, const float* __restrict__ qw,
                        const float* __restrict__ ow, const int* __restrict__ ids,
                        unsigned short* __restrict__ xhi, unsigned short* __restrict__ xlo,
                        unsigned short* __restrict__ whi, unsigned short* __restrict__ wlo,
                        unsigned short* __restrict__ owb, int* __restrict__ offs) {
  if (blockIdx.x == 0 && threadIdx.x < 17) {
    int b = threadIdx.x, lo = 0, hi = N_TOK;
    while (lo < hi) { int mid = (lo + hi) >> 1; if (ids[mid] < b) lo = mid + 1; else hi = mid; }
    offs[b] = lo;   // lower_bound(b); offs[0]=0, offs[16]=N
  }
  const int NX4 = N_TOK * E / 4;        // 712704
  const int NW4 = 3 * E * E / 4;        // 147456
  const int NO4 = E * E / 4;            // 16384
  int total = NX4 + NW4 + NO4;
  for (int i = blockIdx.x * blockDim.x + threadIdx.x; i < total;
       i += gridDim.x * blockDim.x) {
    if (i < NX4) {
      float4 v = ((const float4*)x)[i];
      ushort4 hv, lv;
      hv.x = f2bf(v.x); lv.x = f2bf(v.x - bf2f(hv.x));
      hv.y = f2bf(v.y); lv.y = f2bf(v.y - bf2f(hv.y));
      hv.z = f2bf(v.z); lv.z = f2bf(v.z - bf2f(hv.z));
      hv.w = f2bf(v.w); lv.w = f2bf(v.w - bf2f(hv.w));
      ((ushort4*)xhi)[i] = hv; ((ushort4*)xlo)[i] = lv;
    } else if (i < NX4 + NW4) {
      int j = i - NX4;
      float4 v = ((const float4*)qw)[j];
      ushort4 hv, lv;
      hv.x = f2bf(v.x); lv.x = f2bf(v.x - bf2f(hv.x));
      hv.y = f2bf(v.y); lv.y = f2bf(v.y - bf2f(hv.y));
      hv.z = f2bf(v.z); lv.z = f2bf(v.z - bf2f(hv.z));
      hv.w = f2bf(v.w); lv.w = f2bf(v.w - bf2f(hv.w));
      ((ushort4*)whi)[j] = hv; ((ushort4*)wlo)[j] = lv;
    } else {
      int j = i - NX4 - NW4;
      float4 v = ((const float4*)ow)[j];
      ushort4 hv;
      hv.x = f2bf(v.x); hv.y = f2bf(v.y); hv.z = f2bf(v.z); hv.w = f2bf(v.w);
      ((ushort4*)owb)[j] = hv;
    }
  }
}

// ---------------- K2: qkv projection ----------------
// Tile M=192 (4 waves x 3 m-tiles of 16), N=32 (2 t-tiles), K=256 (whole).
// LDS = 2 x 32 x 264 x 2B = 33.8KB -> 4 blocks/CU. Virtual grid 24x64; XCD
// swizzle: xcd=bid&7 covers all 24 col-blocks of 8 contiguous tiles.
#define QK_BSTRIDE 264   // 256 + 8 pad
#define QSCALE (0.17677669529663687f * 1.4426950408889634f)   // 1/sqrt(32)*log2(e)
__global__ __launch_bounds__(256, 4) void k_qkv(
    const unsigned short* __restrict__ xhi, const unsigned short* __restrict__ xlo,
    const unsigned short* __restrict__ whi, const unsigned short* __restrict__ wlo,
    const float* __restrict__ qkv_b,
    unsigned short* __restrict__ Qb, unsigned short* __restrict__ Kb,
    unsigned short* __restrict__ Vt) {
  int bid = blockIdx.x + 24 * blockIdx.y;
  int xcd = bid & 7;
  int j8 = bid >> 3;                      // 0..191
  int colb = j8 % 24;
  int tile = (j8 / 24) * 8 + xcd;         // 0..63
  if (tile >= 58) return;                 // 58*192 == 11136
  int col0 = colb * 32;
  __shared__ __align__(16) unsigned short Bhi[32 * QK_BSTRIDE];
  __shared__ __align__(16) unsigned short Blo[32 * QK_BSTRIDE];
  int tid = threadIdx.x;
  int w = tid >> 6, lane = tid & 63, m = lane & 15, quad = lane >> 4;
  int rowb = tile * 192 + w * 48;

  // stage pre-split weight tile: 32 rows x 256 cols, 16B copies
  {
    const u16x8* wh8 = (const u16x8*)(whi + (size_t)col0 * E);
    const u16x8* wl8 = (const u16x8*)(wlo + (size_t)col0 * E);
#pragma unroll
    for (int i = 0; i < 4; ++i) {       // 32*32 u16x8 chunks / 256 threads
      int flat = i * 256 + tid;
      int row = flat >> 5, c8 = flat & 31;
      *(u16x8*)(Bhi + row * QK_BSTRIDE + c8 * 8) = wh8[flat];
      *(u16x8*)(Blo + row * QK_BSTRIDE + c8 * 8) = wl8[flat];
    }
  }
  __syncthreads();

  f32x4 acc[3][2] = {};
  bf16x8 ahn[3], aln[3];
#pragma unroll
  for (int mt = 0; mt < 3; ++mt) {      // prefetch kc=0
    const size_t ro = (size_t)(rowb + mt * 16 + m) * E + quad * 8;
    ahn[mt] = ld8(xhi + ro);
    aln[mt] = ld8(xlo + ro);
  }
  for (int kc = 0; kc < 8; ++kc) {
    bf16x8 ah[3], al[3];
#pragma unroll
    for (int mt = 0; mt < 3; ++mt) { ah[mt] = ahn[mt]; al[mt] = aln[mt]; }
    int kon = (kc < 7 ? kc + 1 : kc) * 32 + quad * 8;   // prefetch next kc
#pragma unroll
    for (int mt = 0; mt < 3; ++mt) {
      const size_t ro = (size_t)(rowb + mt * 16 + m) * E + kon;
      ahn[mt] = ld8(xhi + ro);
      aln[mt] = ld8(xlo + ro);
    }
    int ko = kc * 32 + quad * 8;
#pragma unroll
    for (int t = 0; t < 2; ++t) {
      bf16x8 bh = ld8(Bhi + (16 * t + m) * QK_BSTRIDE + ko);
      bf16x8 bl = ld8(Blo + (16 * t + m) * QK_BSTRIDE + ko);
#pragma unroll
      for (int mt = 0; mt < 3; ++mt) {
        acc[mt][t] = __builtin_amdgcn_mfma_f32_16x16x32_bf16(ah[mt], bh, acc[mt][t], 0, 0, 0);
        acc[mt][t] = __builtin_amdgcn_mfma_f32_16x16x32_bf16(ah[mt], bl, acc[mt][t], 0, 0, 0);
        acc[mt][t] = __builtin_amdgcn_mfma_f32_16x16x32_bf16(al[mt], bh, acc[mt][t], 0, 0, 0);
      }
    }
  }
  // epilogue: C layout col=lane&15, row=quad*4+reg. 16-col groups (start mult of 16)
  // never straddle q/k/v 32-boundaries -> wave-uniform routing per t.
#pragma unroll
  for (int t = 0; t < 2; ++t) {
    int j = col0 + 16 * t + m;
    int hd = j / 96;
    int rr = j - hd * 96;
    float bias = qkv_b[j];
#pragma unroll
    for (int mt = 0; mt < 3; ++mt) {
      int tokb = rowb + mt * 16 + quad * 4;
      if (rr < 64) {
        float qsc = (rr < 32) ? QSCALE : 1.0f;   // fold logits scale into Q
        unsigned short* dst = (rr < 32) ? (Qb + (size_t)hd * N_TOK * HD + rr)
                                        : (Kb + (size_t)hd * N_TOK * HD + (rr - 32));
#pragma unroll
        for (int r = 0; r < 4; ++r)
          dst[(size_t)(tokb + r) * HD] = f2bf((acc[mt][t][r] + bias) * qsc);
      } else {
        int d = rr - 64;
        ushort4 pk;
        pk.x = f2bf(acc[mt][t][0] + bias); pk.y = f2bf(acc[mt][t][1] + bias);
        pk.z = f2bf(acc[mt][t][2] + bias); pk.w = f2bf(acc[mt][t][3] + bias);
        *(ushort4*)(Vt + (size_t)(hd * HD + d) * N_TOK + tokb) = pk;
      }
    }
  }
}

// ---------------- K3: flash attention, block-shared K/V staging ----------------
// Grid (head, tile): XCD k holds ONLY head k's K/V (2.1MB, L2-resident).
// 64 q-rows/block, double-buffered 64-key K/V chunks, V rows padded (VSTR=72)
// for conflict-free PV reads. No-max softmax (|s|<~5 in exp2 domain), v_exp_f32.
#define PSTRIDE 72
#define VSTR 72
__global__ __launch_bounds__(256, 4) void k_attn(
    const int* __restrict__ ids, const int* __restrict__ offs,
    const unsigned short* __restrict__ Qb, const unsigned short* __restrict__ Kb,
    const unsigned short* __restrict__ Vt,
    unsigned short* __restrict__ attnb) {
  __shared__ __align__(16) unsigned short Kl[2][64 * 32];   // [buf][key][d]
  __shared__ __align__(16) unsigned short Vl[2][32 * VSTR]; // [buf][d][key+pad]
  __shared__ __align__(16) unsigned short ldsP[4][16 * PSTRIDE];
  __shared__ int bred[8];
  int tid = threadIdx.x;
  int w = tid >> 6, lane = tid & 63;
  int m = lane & 15, quad = lane >> 4;
  int h = blockIdx.x;                     // x fastest -> XCD affinity by head
  int tok0 = blockIdx.y * 64;
  int q0 = tok0 + w * 16;
  unsigned short* P = ldsP[w];
  int tok = q0 + m;                       // this lane's q-row
  int b = ids[tok];
  int st = offs[b], en = offs[b + 1];
  int kmin = st, kmax = en, stM = st, enm = en;
#pragma unroll
  for (int d = 1; d <= 8; d <<= 1) {      // st/en depend only on m
    kmin = min(kmin, __shfl_xor(kmin, d));
    kmax = max(kmax, __shfl_xor(kmax, d));
    stM  = max(stM,  __shfl_xor(stM,  d));
    enm  = min(enm,  __shfl_xor(enm,  d));
  }
  if (lane == 0) { bred[w] = kmin; bred[4 + w] = kmax; }
  __syncthreads();
  int kminB = min(min(bred[0], bred[1]), min(bred[2], bred[3]));
  int kmaxB = max(max(bred[4], bred[5]), max(bred[6], bred[7]));
  int k0beg = kminB & ~63;                // N_TOK % 64 == 0: chunk loads in-bounds

  const unsigned short* Kbase = Kb + (size_t)h * N_TOK * HD;
  const unsigned short* Vbase = Vt + (size_t)h * HD * N_TOK;
  bf16x8 qf = ld8(Qb + (size_t)(h * N_TOK + tok) * HD + quad * 8);

  // staging layout: this lane stages 16B of K and 16B of V per chunk
  int krow = w * 16 + (lane >> 2);        // key index within chunk
  int kgof = (lane & 3) * 8;              // d offset
  int vrow = w * 8 + (lane >> 3);         // d row
  int vgof = (lane & 7) * 8;              // key offset within chunk

  // prologue: stage chunk 0 into buf 0
  bf16x8 kg = ld8(Kbase + (size_t)(k0beg + krow) * HD + kgof);
  bf16x8 vg = ld8(Vbase + (size_t)vrow * N_TOK + k0beg + vgof);
  *(bf16x8*)(&Kl[0][krow * 32 + kgof]) = kg;
  *(bf16x8*)(&Vl[0][vrow * VSTR + vgof]) = vg;
  __syncthreads();

  float lsum = 0.f;
  f32x4 o0 = {}, o1 = {};
  int buf = 0;
  for (int k0 = k0beg; k0 < kmaxB; k0 += 64) {
    int k1 = (k0 + 64 < kmaxB) ? (k0 + 64) : k0;  // clamped block-uniform prefetch
    kg = ld8(Kbase + (size_t)(k1 + krow) * HD + kgof);
    vg = ld8(Vbase + (size_t)vrow * N_TOK + k1 + vgof);
    const unsigned short* Kc = &Kl[buf][0];
    const unsigned short* Vc = &Vl[buf][0];
    f32x4 s[4];
#pragma unroll
    for (int i = 0; i < 4; ++i) {
      bf16x8 kf = ld8(Kc + (16 * i + m) * 32 + quad * 8);
      f32x4 z = {};
      s[i] = __builtin_amdgcn_mfma_f32_16x16x32_bf16(kf, qf, z, 0, 0, 0);
    }
    bool interior = (k0 >= stM && k0 + 64 <= enm);  // per-wave; outside-range
    int jb = k0 + quad * 4;                         // chunks mask to all-zero p
#pragma unroll
    for (int i = 0; i < 4; ++i) {
      float p[4];
#pragma unroll
      for (int r = 0; r < 4; ++r) {
        float sv = s[i][r];
        if (!interior) {
          int j = jb + 16 * i + r;
          sv = (j >= st && j < en) ? sv : -3e38f;   // v_exp(-3e38) == 0
        }
        float e;
        asm("v_exp_f32 %0, %1" : "=v"(e) : "v"(sv));
        p[r] = e;
      }
      lsum += (p[0] + p[1]) + (p[2] + p[3]);
      // nearest (ties-up) bf16 pack
      unsigned int b0 = __float_as_uint(p[0]) + 0x8000u;
      unsigned int b1 = __float_as_uint(p[1]) + 0x8000u;
      unsigned int b2 = __float_as_uint(p[2]) + 0x8000u;
      unsigned int b3 = __float_as_uint(p[3]) + 0x8000u;
      uint2 pk;
      pk.x = (b1 & 0xFFFF0000u) | (b0 >> 16);
      pk.y = (b3 & 0xFFFF0000u) | (b2 >> 16);
      *(uint2*)(P + m * PSTRIDE + 16 * i + quad * 4) = pk;   // P^T[q=m][key]
    }
#pragma unroll
    for (int c = 0; c < 2; ++c) {         // two 32-key sub-chunks
      bf16x8 pf  = ld8(P + m * PSTRIDE + 32 * c + quad * 8);        // B: P^T[q][k]
      bf16x8 vf0 = ld8(Vc + m * VSTR + 32 * c + quad * 8);          // A: V[d][k]
      bf16x8 vf1 = ld8(Vc + (16 + m) * VSTR + 32 * c + quad * 8);
      o0 = __builtin_amdgcn_mfma_f32_16x16x32_bf16(vf0, pf, o0, 0, 0, 0);  // d 0..15
      o1 = __builtin_amdgcn_mfma_f32_16x16x32_bf16(vf1, pf, o1, 0, 0, 0);  // d 16..31
    }
    // stage next chunk into the other buffer (written this iter, read next)
    *(bf16x8*)(&Kl[buf ^ 1][krow * 32 + kgof]) = kg;
    *(bf16x8*)(&Vl[buf ^ 1][vrow * VSTR + vgof]) = vg;
    __syncthreads();
    buf ^= 1;
  }
  lsum += __shfl_xor(lsum, 16);
  lsum += __shfl_xor(lsum, 32);           // quads hold disjoint key partial sums
  float inv = 1.0f / lsum;                // every q-row has >=1 valid key
  ushort4 pk0, pk1;
  pk0.x = f2bf(o0[0] * inv); pk0.y = f2bf(o0[1] * inv);
  pk0.z = f2bf(o0[2] * inv); pk0.w = f2bf(o0[3] * inv);
  pk1.x = f2bf(o1[0] * inv); pk1.y = f2bf(o1[1] * inv);
  pk1.z = f2bf(o1[2] * inv); pk1.w = f2bf(o1[3] * inv);
  // O^T: col=q(lane&15)=this lane's tok; row=d=quad*4+r (+16 for o1)
  *(ushort4*)(attnb + (size_t)tok * E + h * HD + quad * 4) = pk0;
  *(ushort4*)(attnb + (size_t)tok * E + h * HD + 16 + quad * 4) = pk1;
}

// ---------------- K4: output projection ----------------
// Tile M=64 (4 waves x 1 m-tile), N=64 (4 t-tiles), K=256 whole.
// Pre-converted owb copied into LDS; A-loads register-prefetched one kc ahead.
__global__ __launch_bounds__(256, 4) void k_oproj(
    const unsigned short* __restrict__ attnb, const unsigned short* __restrict__ owb,
    const float* __restrict__ ob, float* __restrict__ out) {
  __shared__ __align__(16) unsigned short Bo[64 * QK_BSTRIDE];
  int tid = threadIdx.x;
  int w = tid >> 6, lane = tid & 63, m = lane & 15, quad = lane >> 4;
  int tok0 = blockIdx.x * 64, col0 = blockIdx.y * 64;
  {
    const u16x8* o8 = (const u16x8*)(owb + (size_t)col0 * E);
#pragma unroll
    for (int i = 0; i < 8; ++i) {         // 64*32 u16x8 chunks / 256 threads
      int flat = i * 256 + tid;
      int row = flat >> 5, c8 = flat & 31;
      *(u16x8*)(Bo + row * QK_BSTRIDE + c8 * 8) = o8[flat];
    }
  }
  __syncthreads();
  f32x4 acc[4] = {};
  int arow = tok0 + 16 * w + m;
  const unsigned short* abase = attnb + (size_t)arow * E + quad * 8;
  bf16x8 an = ld8(abase);                 // prefetch kc=0
  for (int kc = 0; kc < 8; ++kc) {
    bf16x8 a = an;
    an = ld8(abase + (kc < 7 ? kc + 1 : kc) * 32);
    int ko = kc * 32 + quad * 8;
#pragma unroll
    for (int t = 0; t < 4; ++t) {
      bf16x8 b = ld8(Bo + (16 * t + m) * QK_BSTRIDE + ko);
      acc[t] = __builtin_amdgcn_mfma_f32_16x16x32_bf16(a, b, acc[t], 0, 0, 0);
    }
  }
#pragma unroll
  for (int t = 0; t < 4; ++t) {
    int j = col0 + 16 * t + m;
    float bias = ob[j];
#pragma unroll
    for (int r = 0; r < 4; ++r) {
      int tok = tok0 + 16 * w + quad * 4 + r;
      out[(size_t)tok * E + j] = acc[t][r] + bias;
    }
  }
}

extern "C" void kernel_launch(void* const* d_in, const int* in_sizes, int n_in,
                              void* d_out, int out_size, void* d_ws, size_t ws_size,
                              hipStream_t stream) {
  const float* x   = (const float*)d_in[0];
  const int*   ids = (const int*)d_in[1];
  const float* qw  = (const float*)d_in[2];
  const float* qb  = (const float*)d_in[3];
  const float* ow  = (const float*)d_in[4];
  const float* ob  = (const float*)d_in[5];
  float* out = (float*)d_out;

  char* p = (char*)d_ws;
  auto alloc = [&](size_t bytes) {
    char* r = p;
    p += (bytes + 255) & ~(size_t)255;
    return r;
  };
  int* offs = (int*)alloc(32 * sizeof(int));
  unsigned short* xhi = (unsigned short*)alloc((size_t)N_TOK * E * 2);
  unsigned short* xlo = (unsigned short*)alloc((size_t)N_TOK * E * 2);
  unsigned short* whi = (unsigned short*)alloc((size_t)3 * E * E * 2);
  unsigned short* wlo = (unsigned short*)alloc((size_t)3 * E * E * 2);
  unsigned short* owb = (unsigned short*)alloc((size_t)E * E * 2);
  unsigned short* Qb  = (unsigned short*)alloc((size_t)N_TOK * E * 2);
  unsigned short* Kb  = (unsigned short*)alloc((size_t)N_TOK * E * 2);
  unsigned short* Vt  = (unsigned short*)alloc((size_t)N_TOK * E * 2);
  unsigned short* att = (unsigned short*)alloc((size_t)N_TOK * E * 2);

  k_split<<<dim3(1712), dim3(256), 0, stream>>>(x, qw, ow, ids, xhi, xlo, whi, wlo, owb, offs);
  k_qkv<<<dim3(24, 64), dim3(256), 0, stream>>>(xhi, xlo, whi, wlo, qb, Qb, Kb, Vt);
  k_attn<<<dim3(H, N_TOK / 64), dim3(256), 0, stream>>>(ids, offs, Qb, Kb, Vt, att);
  k_oproj<<<dim3(N_TOK / 64, E / 64), dim3(256), 0, stream>>>(att, owb, ob, out);
}

// Round 14
// 155.296 us; speedup vs baseline: 1.0598x; 1.0272x over previous
//
#include <hip/hip_runtime.h>
#include <stdint.h>

// Ragged-batch MHA: N=11136 tokens, 16 segments (contiguous, batch_ids sorted),
// E=256, H=8, hd=32. Pipeline (round-9 config + async K staging):
//   K1: k_split — vectorized pre-split x->xhi/xlo, qkv_w->whi/wlo, o_w->owb;
//       block 0 also computes the 17 segment offsets (binary search).
//   K2: qkv = x @ qkv_w^T + b, 3-MFMA split path, all-bf16, B tile in LDS,
//       M=192/N=48, A register-prefetched; XCD-affine block swizzle.
//   K3: flash attention, transposed scores, no-max softmax, 64 q-rows/block,
//       K chunk staged via __builtin_amdgcn_global_load_lds (async DMA,
//       wave-uniform base + lane*16B), V via VGPR round-trip into padded rows.
//   K4: out = attn @ o_w^T + o_b, owb staged into LDS, A prefetched.

#define N_TOK 11136
#define E 256
#define H 8
#define HD 32

typedef __attribute__((ext_vector_type(8))) __bf16 bf16x8;
typedef __attribute__((ext_vector_type(8))) unsigned short u16x8;
typedef __attribute__((ext_vector_type(4))) float f32x4;

__device__ __forceinline__ unsigned short f2bf(float f) {
  unsigned int u = __float_as_uint(f);
  u = (u + 0x7FFFu + ((u >> 16) & 1u)) >> 16;   // RNE
  return (unsigned short)u;
}
__device__ __forceinline__ float bf2f(unsigned short s) {
  return __uint_as_float(((unsigned int)s) << 16);
}
__device__ __forceinline__ bf16x8 ld8(const unsigned short* p) {
  return *(const bf16x8*)p;
}
__device__ __forceinline__ void async_g2l16(const unsigned short* g, unsigned short* l) {
  // 16B per lane: HW writes lane i -> ldsbase + i*16 (wave-uniform lds base).
  __builtin_amdgcn_global_load_lds(
      (const __attribute__((address_space(1))) void*)g,
      (__attribute__((address_space(3))) void*)l, 16, 0, 0);
}

// ---------------- K1: vectorized hi/lo split + segment offsets ----------------
__global__ void k_split(const float* __restrict__ x, const float* __restrict__ qw,
                        const float* __restrict__ ow, const int* __restrict__ ids,
                        unsigned short* __restrict__ xhi, unsigned short* __restrict__ xlo,
                        unsigned short* __restrict__ whi, unsigned short* __restrict__ wlo,
                        unsigned short* __restrict__ owb, int* __restrict__ offs) {
  if (blockIdx.x == 0 && threadIdx.x < 17) {
    int b = threadIdx.x, lo = 0, hi = N_TOK;
    while (lo < hi) { int mid = (lo + hi) >> 1; if (ids[mid] < b) lo = mid + 1; else hi = mid; }
    offs[b] = lo;   // lower_bound(b); offs[0]=0, offs[16]=N
  }
  const int NX4 = N_TOK * E / 4;        // 712704
  const int NW4 = 3 * E * E / 4;        // 147456
  const int NO4 = E * E / 4;            // 16384
  int total = NX4 + NW4 + NO4;
  for (int i = blockIdx.x * blockDim.x + threadIdx.x; i < total;
       i += gridDim.x * blockDim.x) {
    if (i < NX4) {
      float4 v = ((const float4*)x)[i];
      ushort4 hv, lv;
      hv.x = f2bf(v.x); lv.x = f2bf(v.x - bf2f(hv.x));
      hv.y = f2bf(v.y); lv.y = f2bf(v.y - bf2f(hv.y));
      hv.z = f2bf(v.z); lv.z = f2bf(v.z - bf2f(hv.z));
      hv.w = f2bf(v.w); lv.w = f2bf(v.w - bf2f(hv.w));
      ((ushort4*)xhi)[i] = hv; ((ushort4*)xlo)[i] = lv;
    } else if (i < NX4 + NW4) {
      int j = i - NX4;
      float4 v = ((const float4*)qw)[j];
      ushort4 hv, lv;
      hv.x = f2bf(v.x); lv.x = f2bf(v.x - bf2f(hv.x));
      hv.y = f2bf(v.y); lv.y = f2bf(v.y - bf2f(hv.y));
      hv.z = f2bf(v.z); lv.z = f2bf(v.z - bf2f(hv.z));
      hv.w = f2bf(v.w); lv.w = f2bf(v.w - bf2f(hv.w));
      ((ushort4*)whi)[j] = hv; ((ushort4*)wlo)[j] = lv;
    } else {
      int j = i - NX4 - NW4;
      float4 v = ((const float4*)ow)[j];
      ushort4 hv;
      hv.x = f2bf(v.x); hv.y = f2bf(v.y); hv.z = f2bf(v.z); hv.w = f2bf(v.w);
      ((ushort4*)owb)[j] = hv;
    }
  }
}

// ---------------- K2: qkv projection (round-9 config) ----------------
// Tile M=192 (4 waves x 3 m-tiles of 16), N=48 (3 t-tiles), K=256 (whole).
// Virtual grid 16x64 = 1024 blocks; XCD-affine swizzle: xcd=bid&7 sees all 16
// col-blocks of tiles {xcd, 8+xcd, ..., 56+xcd} -> per-XCD L2 footprint 2.4MB.
#define QK_BSTRIDE 264   // 256 + 8 pad
#define QSCALE (0.17677669529663687f * 1.4426950408889634f)   // 1/sqrt(32)*log2(e)
__global__ __launch_bounds__(256, 3) void k_qkv(
    const unsigned short* __restrict__ xhi, const unsigned short* __restrict__ xlo,
    const unsigned short* __restrict__ whi, const unsigned short* __restrict__ wlo,
    const float* __restrict__ qkv_b,
    unsigned short* __restrict__ Qb, unsigned short* __restrict__ Kb,
    unsigned short* __restrict__ Vt) {
  int bid = blockIdx.x + 16 * blockIdx.y;
  int xcd = bid & 7;
  int j8 = bid >> 3;                      // 0..127
  int colb = j8 & 15;
  int tile = (j8 >> 4) * 8 + xcd;         // 0..63
  if (tile >= 58) return;                 // 58*192 == 11136
  int col0 = colb * 48;
  __shared__ __align__(16) unsigned short Bhi[48 * QK_BSTRIDE];
  __shared__ __align__(16) unsigned short Blo[48 * QK_BSTRIDE];
  int tid = threadIdx.x;
  int w = tid >> 6, lane = tid & 63, m = lane & 15, quad = lane >> 4;
  int rowb = tile * 192 + w * 48;

  // stage pre-split weight tile: 48 rows x 256 cols, 16B copies
  {
    const u16x8* wh8 = (const u16x8*)(whi + (size_t)col0 * E);
    const u16x8* wl8 = (const u16x8*)(wlo + (size_t)col0 * E);
#pragma unroll
    for (int i = 0; i < 6; ++i) {       // 48*32 u16x8 chunks / 256 threads
      int flat = i * 256 + tid;
      int row = flat >> 5, c8 = flat & 31;
      *(u16x8*)(Bhi + row * QK_BSTRIDE + c8 * 8) = wh8[flat];
      *(u16x8*)(Blo + row * QK_BSTRIDE + c8 * 8) = wl8[flat];
    }
  }
  __syncthreads();

  f32x4 acc[3][3] = {};
  bf16x8 ahn[3], aln[3];
#pragma unroll
  for (int mt = 0; mt < 3; ++mt) {      // prefetch kc=0
    const size_t ro = (size_t)(rowb + mt * 16 + m) * E + quad * 8;
    ahn[mt] = ld8(xhi + ro);
    aln[mt] = ld8(xlo + ro);
  }
  for (int kc = 0; kc < 8; ++kc) {
    bf16x8 ah[3], al[3];
#pragma unroll
    for (int mt = 0; mt < 3; ++mt) { ah[mt] = ahn[mt]; al[mt] = aln[mt]; }
    int kon = (kc < 7 ? kc + 1 : kc) * 32 + quad * 8;   // prefetch next kc
#pragma unroll
    for (int mt = 0; mt < 3; ++mt) {
      const size_t ro = (size_t)(rowb + mt * 16 + m) * E + kon;
      ahn[mt] = ld8(xhi + ro);
      aln[mt] = ld8(xlo + ro);
    }
    int ko = kc * 32 + quad * 8;
#pragma unroll
    for (int t = 0; t < 3; ++t) {
      bf16x8 bh = ld8(Bhi + (16 * t + m) * QK_BSTRIDE + ko);
      bf16x8 bl = ld8(Blo + (16 * t + m) * QK_BSTRIDE + ko);
#pragma unroll
      for (int mt = 0; mt < 3; ++mt) {
        acc[mt][t] = __builtin_amdgcn_mfma_f32_16x16x32_bf16(ah[mt], bh, acc[mt][t], 0, 0, 0);
        acc[mt][t] = __builtin_amdgcn_mfma_f32_16x16x32_bf16(ah[mt], bl, acc[mt][t], 0, 0, 0);
        acc[mt][t] = __builtin_amdgcn_mfma_f32_16x16x32_bf16(al[mt], bh, acc[mt][t], 0, 0, 0);
      }
    }
  }
  // epilogue: C layout col=lane&15, row=quad*4+reg. 16-col groups (start mult of 16)
  // never straddle q/k/v 32-boundaries -> wave-uniform routing per t.
#pragma unroll
  for (int t = 0; t < 3; ++t) {
    int j = col0 + 16 * t + m;
    int hd = j / 96;
    int rr = j - hd * 96;
    float bias = qkv_b[j];
#pragma unroll
    for (int mt = 0; mt < 3; ++mt) {
      int tokb = rowb + mt * 16 + quad * 4;
      if (rr < 64) {
        float qsc = (rr < 32) ? QSCALE : 1.0f;   // fold logits scale into Q
        unsigned short* dst = (rr < 32) ? (Qb + (size_t)hd * N_TOK * HD + rr)
                                        : (Kb + (size_t)hd * N_TOK * HD + (rr - 32));
#pragma unroll
        for (int r = 0; r < 4; ++r)
          dst[(size_t)(tokb + r) * HD] = f2bf((acc[mt][t][r] + bias) * qsc);
      } else {
        int d = rr - 64;
        ushort4 pk;
        pk.x = f2bf(acc[mt][t][0] + bias); pk.y = f2bf(acc[mt][t][1] + bias);
        pk.z = f2bf(acc[mt][t][2] + bias); pk.w = f2bf(acc[mt][t][3] + bias);
        *(ushort4*)(Vt + (size_t)(hd * HD + d) * N_TOK + tokb) = pk;
      }
    }
  }
}

// ---------------- K3: flash attention, async K staging ----------------
// Grid (head, tile): XCD k holds ONLY head k's K/V (2.1MB, L2-resident).
// 64 q-rows/block, double-buffered 64-key chunks. K staged via
// global_load_lds (async, lane*16B into [key][d] rows); V staged via VGPR
// into padded rows (VSTR=72, conflict-free PV reads — pad is incompatible
// with global_load_lds' lane*16 scatter). __syncthreads drains vmcnt.
#define PSTRIDE 72
#define VSTR 72
__global__ __launch_bounds__(256, 4) void k_attn(
    const int* __restrict__ ids, const int* __restrict__ offs,
    const unsigned short* __restrict__ Qb, const unsigned short* __restrict__ Kb,
    const unsigned short* __restrict__ Vt,
    unsigned short* __restrict__ attnb) {
  __shared__ __align__(16) unsigned short Kl[2][64 * 32];   // [buf][key][d]
  __shared__ __align__(16) unsigned short Vl[2][32 * VSTR]; // [buf][d][key+pad]
  __shared__ __align__(16) unsigned short ldsP[4][16 * PSTRIDE];
  __shared__ int bred[8];
  int tid = threadIdx.x;
  int w = tid >> 6, lane = tid & 63;
  int m = lane & 15, quad = lane >> 4;
  int h = blockIdx.x;                     // x fastest -> XCD affinity by head
  int tok0 = blockIdx.y * 64;
  int q0 = tok0 + w * 16;
  unsigned short* P = ldsP[w];
  int tok = q0 + m;                       // this lane's q-row
  int b = ids[tok];
  int st = offs[b], en = offs[b + 1];
  int kmin = st, kmax = en, stM = st, enm = en;
#pragma unroll
  for (int d = 1; d <= 8; d <<= 1) {      // st/en depend only on m
    kmin = min(kmin, __shfl_xor(kmin, d));
    kmax = max(kmax, __shfl_xor(kmax, d));
    stM  = max(stM,  __shfl_xor(stM,  d));
    enm  = min(enm,  __shfl_xor(enm,  d));
  }
  if (lane == 0) { bred[w] = kmin; bred[4 + w] = kmax; }
  __syncthreads();
  int kminB = min(min(bred[0], bred[1]), min(bred[2], bred[3]));
  int kmaxB = max(max(bred[4], bred[5]), max(bred[6], bred[7]));
  int k0beg = kminB & ~63;                // N_TOK % 64 == 0: chunk loads in-bounds

  const unsigned short* Kbase = Kb + (size_t)h * N_TOK * HD;
  const unsigned short* Vbase = Vt + (size_t)h * HD * N_TOK;
  bf16x8 qf = ld8(Qb + (size_t)(h * N_TOK + tok) * HD + quad * 8);

  // staging layout: this lane stages 16B of K (async DMA) and 16B of V (VGPR)
  int krow = w * 16 + (lane >> 2);        // key index within chunk
  int kgof = (lane & 3) * 8;              // d offset
  // K LDS region for this wave: Kl[buf] + w*512 shorts; lane i lands at +i*16B
  // ((lane>>2)*64B + (lane&3)*16B == lane*16B) — matches [key][d] exactly.
  int vrow = w * 8 + (lane >> 3);         // d row
  int vgof = (lane & 7) * 8;              // key offset within chunk

  // prologue: stage chunk 0 into buf 0
  async_g2l16(Kbase + (size_t)(k0beg + krow) * HD + kgof, &Kl[0][w * 512]);
  bf16x8 vg = ld8(Vbase + (size_t)vrow * N_TOK + k0beg + vgof);
  *(bf16x8*)(&Vl[0][vrow * VSTR + vgof]) = vg;
  __syncthreads();                        // drains vmcnt (incl. async K)

  float lsum = 0.f;
  f32x4 o0 = {}, o1 = {};
  int buf = 0;
  for (int k0 = k0beg; k0 < kmaxB; k0 += 64) {
    int k1 = (k0 + 64 < kmaxB) ? (k0 + 64) : k0;  // clamped block-uniform prefetch
    // async K for next chunk -> other buffer (its readers passed the last barrier)
    async_g2l16(Kbase + (size_t)(k1 + krow) * HD + kgof, &Kl[buf ^ 1][w * 512]);
    vg = ld8(Vbase + (size_t)vrow * N_TOK + k1 + vgof);
    const unsigned short* Kc = &Kl[buf][0];
    const unsigned short* Vc = &Vl[buf][0];
    f32x4 s[4];
#pragma unroll
    for (int i = 0; i < 4; ++i) {
      bf16x8 kf = ld8(Kc + (16 * i + m) * 32 + quad * 8);
      f32x4 z = {};
      s[i] = __builtin_amdgcn_mfma_f32_16x16x32_bf16(kf, qf, z, 0, 0, 0);
    }
    bool interior = (k0 >= stM && k0 + 64 <= enm);  // per-wave; outside-range
    int jb = k0 + quad * 4;                         // chunks mask to all-zero p
#pragma unroll
    for (int i = 0; i < 4; ++i) {
      float p[4];
#pragma unroll
      for (int r = 0; r < 4; ++r) {
        float sv = s[i][r];
        if (!interior) {
          int j = jb + 16 * i + r;
          sv = (j >= st && j < en) ? sv : -3e38f;   // v_exp(-3e38) == 0
        }
        float e;
        asm("v_exp_f32 %0, %1" : "=v"(e) : "v"(sv));
        p[r] = e;
      }
      lsum += (p[0] + p[1]) + (p[2] + p[3]);
      // nearest (ties-up) bf16 pack
      unsigned int b0 = __float_as_uint(p[0]) + 0x8000u;
      unsigned int b1 = __float_as_uint(p[1]) + 0x8000u;
      unsigned int b2 = __float_as_uint(p[2]) + 0x8000u;
      unsigned int b3 = __float_as_uint(p[3]) + 0x8000u;
      uint2 pk;
      pk.x = (b1 & 0xFFFF0000u) | (b0 >> 16);
      pk.y = (b3 & 0xFFFF0000u) | (b2 >> 16);
      *(uint2*)(P + m * PSTRIDE + 16 * i + quad * 4) = pk;   // P^T[q=m][key]
    }
#pragma unroll
    for (int c = 0; c < 2; ++c) {         // two 32-key sub-chunks
      bf16x8 pf  = ld8(P + m * PSTRIDE + 32 * c + quad * 8);        // B: P^T[q][k]
      bf16x8 vf0 = ld8(Vc + m * VSTR + 32 * c + quad * 8);          // A: V[d][k]
      bf16x8 vf1 = ld8(Vc + (16 + m) * VSTR + 32 * c + quad * 8);
      o0 = __builtin_amdgcn_mfma_f32_16x16x32_bf16(vf0, pf, o0, 0, 0, 0);  // d 0..15
      o1 = __builtin_amdgcn_mfma_f32_16x16x32_bf16(vf1, pf, o1, 0, 0, 0);  // d 16..31
    }
    // V for next chunk into the other buffer
    *(bf16x8*)(&Vl[buf ^ 1][vrow * VSTR + vgof]) = vg;
    __syncthreads();                      // drains async K + V write + P reads
    buf ^= 1;
  }
  lsum += __shfl_xor(lsum, 16);
  lsum += __shfl_xor(lsum, 32);           // quads hold disjoint key partial sums
  float inv = 1.0f / lsum;                // every q-row has >=1 valid key
  ushort4 pk0, pk1;
  pk0.x = f2bf(o0[0] * inv); pk0.y = f2bf(o0[1] * inv);
  pk0.z = f2bf(o0[2] * inv); pk0.w = f2bf(o0[3] * inv);
  pk1.x = f2bf(o1[0] * inv); pk1.y = f2bf(o1[1] * inv);
  pk1.z = f2bf(o1[2] * inv); pk1.w = f2bf(o1[3] * inv);
  // O^T: col=q(lane&15)=this lane's tok; row=d=quad*4+r (+16 for o1)
  *(ushort4*)(attnb + (size_t)tok * E + h * HD + quad * 4) = pk0;
  *(ushort4*)(attnb + (size_t)tok * E + h * HD + 16 + quad * 4) = pk1;
}

// ---------------- K4: output projection ----------------
// Tile M=64 (4 waves x 1 m-tile), N=64 (4 t-tiles), K=256 whole.
// Pre-converted owb copied into LDS; A-loads register-prefetched one kc ahead.
__global__ __launch_bounds__(256, 4) void k_oproj(
    const unsigned short* __restrict__ attnb, const unsigned short* __restrict__ owb,
    const float* __restrict__ ob, float* __restrict__ out) {
  __shared__ __align__(16) unsigned short Bo[64 * QK_BSTRIDE];
  int tid = threadIdx.x;
  int w = tid >> 6, lane = tid & 63, m = lane & 15, quad = lane >> 4;
  int tok0 = blockIdx.x * 64, col0 = blockIdx.y * 64;
  {
    const u16x8* o8 = (const u16x8*)(owb + (size_t)col0 * E);
#pragma unroll
    for (int i = 0; i < 8; ++i) {         // 64*32 u16x8 chunks / 256 threads
      int flat = i * 256 + tid;
      int row = flat >> 5, c8 = flat & 31;
      *(u16x8*)(Bo + row * QK_BSTRIDE + c8 * 8) = o8[flat];
    }
  }
  __syncthreads();
  f32x4 acc[4] = {};
  int arow = tok0 + 16 * w + m;
  const unsigned short* abase = attnb + (size_t)arow * E + quad * 8;
  bf16x8 an = ld8(abase);                 // prefetch kc=0
  for (int kc = 0; kc < 8; ++kc) {
    bf16x8 a = an;
    an = ld8(abase + (kc < 7 ? kc + 1 : kc) * 32);
    int ko = kc * 32 + quad * 8;
#pragma unroll
    for (int t = 0; t < 4; ++t) {
      bf16x8 b = ld8(Bo + (16 * t + m) * QK_BSTRIDE + ko);
      acc[t] = __builtin_amdgcn_mfma_f32_16x16x32_bf16(a, b, acc[t], 0, 0, 0);
    }
  }
#pragma unroll
  for (int t = 0; t < 4; ++t) {
    int j = col0 + 16 * t + m;
    float bias = ob[j];
#pragma unroll
    for (int r = 0; r < 4; ++r) {
      int tok = tok0 + 16 * w + quad * 4 + r;
      out[(size_t)tok * E + j] = acc[t][r] + bias;
    }
  }
}

extern "C" void kernel_launch(void* const* d_in, const int* in_sizes, int n_in,
                              void* d_out, int out_size, void* d_ws, size_t ws_size,
                              hipStream_t stream) {
  const float* x   = (const float*)d_in[0];
  const int*   ids = (const int*)d_in[1];
  const float* qw  = (const float*)d_in[2];
  const float* qb  = (const float*)d_in[3];
  const float* ow  = (const float*)d_in[4];
  const float* ob  = (const float*)d_in[5];
  float* out = (float*)d_out;

  char* p = (char*)d_ws;
  auto alloc = [&](size_t bytes) {
    char* r = p;
    p += (bytes + 255) & ~(size_t)255;
    return r;
  };
  int* offs = (int*)alloc(32 * sizeof(int));
  unsigned short* xhi = (unsigned short*)alloc((size_t)N_TOK * E * 2);
  unsigned short* xlo = (unsigned short*)alloc((size_t)N_TOK * E * 2);
  unsigned short* whi = (unsigned short*)alloc((size_t)3 * E * E * 2);
  unsigned short* wlo = (unsigned short*)alloc((size_t)3 * E * E * 2);
  unsigned short* owb = (unsigned short*)alloc((size_t)E * E * 2);
  unsigned short* Qb  = (unsigned short*)alloc((size_t)N_TOK * E * 2);
  unsigned short* Kb  = (unsigned short*)alloc((size_t)N_TOK * E * 2);
  unsigned short* Vt  = (unsigned short*)alloc((size_t)N_TOK * E * 2);
  unsigned short* att = (unsigned short*)alloc((size_t)N_TOK * E * 2);

  k_split<<<dim3(1712), dim3(256), 0, stream>>>(x, qw, ow, ids, xhi, xlo, whi, wlo, owb, offs);
  k_qkv<<<dim3(16, 64), dim3(256), 0, stream>>>(xhi, xlo, whi, wlo, qb, Qb, Kb, Vt);
  k_attn<<<dim3(H, N_TOK / 64), dim3(256), 0, stream>>>(ids, offs, Qb, Kb, Vt, att);
  k_oproj<<<dim3(N_TOK / 64, E / 64), dim3(256), 0, stream>>>(att, owb, ob, out);
}